// Round 1
// baseline (329.590 us; speedup 1.0000x reference)
//
#include <hip/hip_runtime.h>

typedef __bf16 bf16;
typedef __bf16 bf16x8 __attribute__((ext_vector_type(8)));
typedef __bf16 bf16x4 __attribute__((ext_vector_type(4)));
typedef float f32x4 __attribute__((ext_vector_type(4)));

#define MFMA(a, b, c) __builtin_amdgcn_mfma_f32_16x16x32_bf16((a), (b), (c), 0, 0, 0)

static __device__ __forceinline__ f32x4 zero4() {
    f32x4 z; z[0] = 0.f; z[1] = 0.f; z[2] = 0.f; z[3] = 0.f; return z;
}

// ---------- generic f32 -> bf16 convert (n % 4 == 0) ----------
__global__ void k_cvt(const float* __restrict__ src, bf16* __restrict__ dst, int n) {
    int i = (blockIdx.x * 256 + threadIdx.x) * 4;
    if (i < n) {
        float4 v = *(const float4*)(src + i);
        bf16x4 o; o[0] = (bf16)v.x; o[1] = (bf16)v.y; o[2] = (bf16)v.z; o[3] = (bf16)v.w;
        *(bf16x4*)(dst + i) = o;
    }
}

// ---------- W3 (16512 x 129 f32, n=(i*128+k), j innermost) -> bf16 padded ld=136 ----------
__global__ void k_cvt_w3(const float* __restrict__ src, bf16* __restrict__ dst) {
    int n = blockIdx.x;       // 0..16511
    int t = threadIdx.x;      // 0..191
    if (t < 129) dst[n * 136 + t] = (bf16)src[n * 129 + t];
}

// ---------- MLP: pout[proj][row][p] = leaky_relu(A @ W^T + b), bf16 out ----------
// BT-GEMM M=2048 (64 rows/block), N=128, K=1024. grid (32, 3), block 256.
__global__ __launch_bounds__(256) void k_mlp(
    const bf16* __restrict__ xspb, const bf16* __restrict__ xb,
    const bf16* __restrict__ wbf,   // [3][128][1024]
    const float* __restrict__ bx, const float* __restrict__ by, const float* __restrict__ bz,
    bf16* __restrict__ pout)        // [3][2048][128]
{
    const int proj = blockIdx.y;
    const bf16* A = (proj == 2) ? xb : xspb;
    const bf16* W = wbf + proj * (128 * 1024);
    const float* bias = (proj == 0) ? bx : (proj == 1) ? by : bz;
    bf16* out = pout + proj * (2048 * 128);

    const int tid = threadIdx.x;
    const int wv = tid >> 6, lane = tid & 63, quad = lane >> 4, lr = lane & 15;
    const int m0 = blockIdx.x * 64 + wv * 16;   // this wave's 16 rows

    f32x4 acc[8];
#pragma unroll
    for (int i = 0; i < 8; i++) acc[i] = zero4();

    const bf16* arow = A + (m0 + lr) * 1024 + quad * 8;
    const bf16* brow = W + lr * 1024 + quad * 8;

    for (int kw = 0; kw < 32; kw++) {
        bf16x8 a = *(const bf16x8*)(arow + kw * 32);
#pragma unroll
        for (int nt = 0; nt < 8; nt++) {
            bf16x8 b = *(const bf16x8*)(brow + nt * 16 * 1024 + kw * 32);
            acc[nt] = MFMA(a, b, acc[nt]);
        }
    }
#pragma unroll
    for (int nt = 0; nt < 8; nt++) {
        int col = nt * 16 + lr;
        float bv = bias[col];
#pragma unroll
        for (int r = 0; r < 4; r++) {
            int row = m0 + quad * 4 + r;
            float v = acc[nt][r] + bv;
            v = v > 0.f ? v : 0.1f * v;           // leaky_relu(0.1)
            out[row * 128 + col] = (bf16)v;
        }
    }
}

// ---------- V[b][y][n=(i*128+k)] = sum_{j<128} yp[b,y,j]*W3bf[n,j] + W3bf[n,128] ----------
// BT-GEMM per b: M=128(y), N=16512 (128/block), K=128(j). grid (129, 16), block 256.
__global__ __launch_bounds__(256) void k_vgemm(
    const bf16* __restrict__ yp,     // [16][128][128]
    const bf16* __restrict__ w3b,    // [16512][136]
    bf16* __restrict__ V)            // [16][128][16512]
{
    const int b = blockIdx.y;
    const int n0 = blockIdx.x * 128;
    const int tid = threadIdx.x;
    const int wv = tid >> 6, lane = tid & 63, quad = lane >> 4, lr = lane & 15;
    const int y0 = wv * 32;          // this wave: 32 y rows x 128 n cols

    const bf16* Ab = yp + b * 128 * 128;

    f32x4 acc[2][8];
#pragma unroll
    for (int s = 0; s < 2; s++)
#pragma unroll
        for (int nt = 0; nt < 8; nt++) acc[s][nt] = zero4();

#pragma unroll
    for (int kw = 0; kw < 4; kw++) {
        bf16x8 a0 = *(const bf16x8*)(Ab + (y0 + lr) * 128 + kw * 32 + quad * 8);
        bf16x8 a1 = *(const bf16x8*)(Ab + (y0 + 16 + lr) * 128 + kw * 32 + quad * 8);
#pragma unroll
        for (int nt = 0; nt < 8; nt++) {
            bf16x8 bb = *(const bf16x8*)(w3b + (n0 + nt * 16 + lr) * 136 + kw * 32 + quad * 8);
            acc[0][nt] = MFMA(a0, bb, acc[0][nt]);
            acc[1][nt] = MFMA(a1, bb, acc[1][nt]);
        }
    }
#pragma unroll
    for (int nt = 0; nt < 8; nt++) {
        int n = n0 + nt * 16 + lr;
        float bv = (float)w3b[n * 136 + 128];    // y-side bias (j=128 column)
#pragma unroll
        for (int s = 0; s < 2; s++)
#pragma unroll
            for (int r = 0; r < 4; r++) {
                int y = y0 + s * 16 + quad * 4 + r;
                V[(b * 128 + y) * 16512 + n] = (bf16)(acc[s][nt][r] + bv);
            }
    }
}

// ---------- per (b,y): H[z,i]=sum_k zp[z,k]*V[y,i,k]; out[b,x,y,z]=sum_{i<128} xp[x,i]*H[z,i]+H[z,128] ----------
// grid 2048, block 256 (4 waves). LDS: H 128x136 bf16 = 34816 B.
__global__ __launch_bounds__(256) void k_score(
    const bf16* __restrict__ xp,    // [16][128][128]
    const bf16* __restrict__ zp,    // [16][128][128]
    const bf16* __restrict__ V,     // [16][128][16512]
    float* __restrict__ out)        // [16][128][128][128]  (b,x,y,z)
{
    __shared__ bf16 Hlds[128 * 136];
    const int bi = blockIdx.x;
    const int b = bi >> 7, y = bi & 127;
    const int tid = threadIdx.x;
    const int wv = tid >> 6, lane = tid & 63, quad = lane >> 4, lr = lane & 15;

    const bf16* Zb = zp + b * 16384;
    const bf16* Vby = V + (b * 128 + y) * 16512;

    // ---- GEMM1: H[z, i], z in [wv*32, wv*32+32), i in 0..128 ----
    const int z0 = wv * 32;
    f32x4 acc1[2][9];
#pragma unroll
    for (int s = 0; s < 2; s++)
#pragma unroll
        for (int it = 0; it < 9; it++) acc1[s][it] = zero4();

#pragma unroll
    for (int kw = 0; kw < 4; kw++) {
        bf16x8 a0 = *(const bf16x8*)(Zb + (z0 + lr) * 128 + kw * 32 + quad * 8);
        bf16x8 a1 = *(const bf16x8*)(Zb + (z0 + 16 + lr) * 128 + kw * 32 + quad * 8);
#pragma unroll
        for (int it = 0; it < 8; it++) {
            bf16x8 bb = *(const bf16x8*)(Vby + (it * 16 + lr) * 128 + kw * 32 + quad * 8);
            acc1[0][it] = MFMA(a0, bb, acc1[0][it]);
            acc1[1][it] = MFMA(a1, bb, acc1[1][it]);
        }
        // i-tile 8: only i=128 exists (lr==0)
        bf16x8 b8;
#pragma unroll
        for (int q = 0; q < 8; q++) b8[q] = (bf16)0.f;
        if (lr == 0) b8 = *(const bf16x8*)(Vby + 128 * 128 + kw * 32 + quad * 8);
        acc1[0][8] = MFMA(a0, b8, acc1[0][8]);
        acc1[1][8] = MFMA(a1, b8, acc1[1][8]);
    }
    // write H to LDS (bf16), cols i<=128, padded ld=136
#pragma unroll
    for (int it = 0; it < 9; it++) {
        int i = it * 16 + lr;
        if (i <= 128) {
#pragma unroll
            for (int s = 0; s < 2; s++)
#pragma unroll
                for (int r = 0; r < 4; r++) {
                    int z = z0 + s * 16 + quad * 4 + r;
                    Hlds[z * 136 + i] = (bf16)acc1[s][it][r];
                }
        }
    }
    __syncthreads();

    // ---- GEMM2: out2[x, z] = sum_{i<128} xp[x,i] * H[z,i] ----
    const bf16* Xb = xp + b * 16384;
    const int x0 = wv * 32;
    f32x4 acc2[2][8];
#pragma unroll
    for (int s = 0; s < 2; s++)
#pragma unroll
        for (int zt = 0; zt < 8; zt++) acc2[s][zt] = zero4();

#pragma unroll
    for (int iw = 0; iw < 4; iw++) {
        bf16x8 a0 = *(const bf16x8*)(Xb + (x0 + lr) * 128 + iw * 32 + quad * 8);
        bf16x8 a1 = *(const bf16x8*)(Xb + (x0 + 16 + lr) * 128 + iw * 32 + quad * 8);
#pragma unroll
        for (int zt = 0; zt < 8; zt++) {
            bf16x8 bb = *(const bf16x8*)(&Hlds[(zt * 16 + lr) * 136 + iw * 32 + quad * 8]);
            acc2[0][zt] = MFMA(a0, bb, acc2[0][zt]);
            acc2[1][zt] = MFMA(a1, bb, acc2[1][zt]);
        }
    }
    // epilogue: + H[z,128] (x-side bias, x1[:,128]==1), store out[b,x,y,z]
#pragma unroll
    for (int zt = 0; zt < 8; zt++) {
        int z = zt * 16 + lr;
        float hb = (float)Hlds[z * 136 + 128];
#pragma unroll
        for (int s = 0; s < 2; s++)
#pragma unroll
            for (int r = 0; r < 4; r++) {
                int x = x0 + s * 16 + quad * 4 + r;
                out[((b * 128 + x) * 128 + y) * 128 + z] = acc2[s][zt][r] + hb;
            }
    }
}

extern "C" void kernel_launch(void* const* d_in, const int* in_sizes, int n_in,
                              void* d_out, int out_size, void* d_ws, size_t ws_size,
                              hipStream_t stream) {
    const float* x   = (const float*)d_in[0];
    const float* xsp = (const float*)d_in[1];
    const float* Wx  = (const float*)d_in[2];
    const float* bx  = (const float*)d_in[3];
    const float* Wy  = (const float*)d_in[4];
    const float* by  = (const float*)d_in[5];
    const float* Wz  = (const float*)d_in[6];
    const float* bz  = (const float*)d_in[7];
    const float* W3  = (const float*)d_in[8];
    float* out = (float*)d_out;

    // workspace layout (bytes)
    char* ws = (char*)d_ws;
    bf16* xspb = (bf16*)(ws);                   // 2048*1024 bf16 = 4 MiB
    bf16* xb   = (bf16*)(ws + 4194304);         // 4 MiB
    bf16* wbf  = (bf16*)(ws + 8388608);         // 3*128*1024 = 768 KiB
    bf16* w3b  = (bf16*)(ws + 9175040);         // 16512*136 = 4.28 MiB
    bf16* pout = (bf16*)(ws + 13666304);        // 3*2048*128 = 1.5 MiB (xp,yp,zp)
    bf16* V    = (bf16*)(ws + 15239168);        // 16*128*16512 = 64.5 MiB

    k_cvt<<<2048, 256, 0, stream>>>(xsp, xspb, 2097152);
    k_cvt<<<2048, 256, 0, stream>>>(x, xb, 2097152);
    k_cvt<<<128, 256, 0, stream>>>(Wx, wbf, 131072);
    k_cvt<<<128, 256, 0, stream>>>(Wy, wbf + 131072, 131072);
    k_cvt<<<128, 256, 0, stream>>>(Wz, wbf + 262144, 131072);
    k_cvt_w3<<<16512, 192, 0, stream>>>(W3, w3b);

    k_mlp<<<dim3(32, 3), 256, 0, stream>>>(xspb, xb, wbf, bx, by, bz, pout);
    k_vgemm<<<dim3(129, 16), 256, 0, stream>>>(pout + 262144 /*yp*/, w3b, V);
    k_score<<<2048, 256, 0, stream>>>(pout /*xp*/, pout + 524288 /*zp*/, V, out);
}